// Round 1
// baseline (135.401 us; speedup 1.0000x reference)
//
#include <hip/hip_runtime.h>

#define K 8

__global__ __launch_bounds__(256) void shading_compositor_kernel(
    const int*   __restrict__ idx,
    const float* __restrict__ dists,
    const float* __restrict__ points,
    const float* __restrict__ normals,
    const float* __restrict__ light_location,
    const float* __restrict__ light_ambient,
    const float* __restrict__ light_diffuse,
    const float* __restrict__ light_specular,
    const float* __restrict__ mat_ambient,
    const float* __restrict__ mat_diffuse,
    const float* __restrict__ mat_specular,
    const float* __restrict__ camera_position,
    const int*   __restrict__ shininess_p,
    float*       __restrict__ out,
    int n_pix)
{
    const int p = blockIdx.x * blockDim.x + threadIdx.x;
    if (p >= n_pix) return;

    // ---- uniform constants (L2-broadcast reads) ----
    const float Lx = light_location[0], Ly = light_location[1], Lz = light_location[2];
    const float Cx = camera_position[0], Cy = camera_position[1], Cz = camera_position[2];
    const float amb0 = light_ambient[0] * mat_ambient[0];
    const float amb1 = light_ambient[1] * mat_ambient[1];
    const float amb2 = light_ambient[2] * mat_ambient[2];
    const float dif0 = light_diffuse[0] * mat_diffuse[0];
    const float dif1 = light_diffuse[1] * mat_diffuse[1];
    const float dif2 = light_diffuse[2] * mat_diffuse[2];
    const float spc0 = light_specular[0] * mat_specular[0];
    const float spc1 = light_specular[1] * mat_specular[1];
    const float spc2 = light_specular[2] * mat_specular[2];
    const int   shin = shininess_p[0];

    // ---- vector loads of this pixel's K=8 idx / dists (32B each, coalesced) ----
    const int4*   idxv  = reinterpret_cast<const int4*>(idx   + (size_t)p * K);
    const float4* dstv  = reinterpret_cast<const float4*>(dists + (size_t)p * K);
    int4   i0 = idxv[0], i1 = idxv[1];
    float4 d0 = dstv[0], d1 = dstv[1];

    int   ik[K] = {i0.x, i0.y, i0.z, i0.w, i1.x, i1.y, i1.z, i1.w};
    float dk[K] = {d0.x, d0.y, d0.z, d0.w, d1.x, d1.y, d1.z, d1.w};

    // ---- distance weights: mask -1 -> 0, L1-normalize over K ----
    float w[K];
    float wsum = 0.f;
#pragma unroll
    for (int k = 0; k < K; ++k) {
        float d = dk[k];
        float m = (d != -1.0f) ? d : 0.0f;
        w[k] = m;
        wsum += fabsf(m);
    }
    const float winv = 1.0f / fmaxf(wsum, 1e-12f);

    float acc0 = 0.f, acc1 = 0.f, acc2 = 0.f;

#pragma unroll
    for (int k = 0; k < K; ++k) {
        const int ii = (ik[k] < 0) ? 0 : ik[k];
        const size_t base = (size_t)ii * 3;
        const float px = points[base], py = points[base + 1], pz = points[base + 2];
        const float nx = normals[base], ny = normals[base + 1], nz = normals[base + 2];

        // dir_light = normalize(light - pt), clip(norm, 1e-6)
        float lx = Lx - px, ly = Ly - py, lz = Lz - pz;
        float ll = lx * lx + ly * ly + lz * lz;
        float li = (ll > 1e-12f) ? rsqrtf(ll) : 1e6f;
        lx *= li; ly *= li; lz *= li;

        const float cosv = nx * lx + ny * ly + nz * lz;

        // view = normalize(camera - pt)
        float vx = Cx - px, vy = Cy - py, vz = Cz - pz;
        float vv = vx * vx + vy * vy + vz * vz;
        float vi = (vv > 1e-12f) ? rsqrtf(vv) : 1e6f;
        vx *= vi; vy *= vi; vz *= vi;

        // reflect = 2*cos*n - dir_light
        const float c2 = 2.0f * cosv;
        const float rx = c2 * nx - lx;
        const float ry = c2 * ny - ly;
        const float rz = c2 * nz - lz;

        float alpha = fmaxf(vx * rx + vy * ry + vz * rz, 0.0f);
        if (!(cosv > 0.0f)) alpha = 0.0f;

        // alpha ** shininess by squaring (shin is wave-uniform)
        float sp = 1.0f, b = alpha;
        int e = shin;
        while (e > 0) {
            if (e & 1) sp *= b;
            b *= b;
            e >>= 1;
        }

        const float rc = fmaxf(cosv, 0.0f);
        const float wn = w[k] * winv;
        acc0 += wn * (amb0 + dif0 * rc + spc0 * sp);
        acc1 += wn * (amb1 + dif1 * rc + spc1 * sp);
        acc2 += wn * (amb2 + dif2 * rc + spc2 * sp);
    }

    float* o = out + (size_t)p * 3;
    o[0] = acc0;
    o[1] = acc1;
    o[2] = acc2;
}

extern "C" void kernel_launch(void* const* d_in, const int* in_sizes, int n_in,
                              void* d_out, int out_size, void* d_ws, size_t ws_size,
                              hipStream_t stream) {
    const int*   idx             = (const int*)d_in[0];
    const float* dists           = (const float*)d_in[1];
    const float* points          = (const float*)d_in[2];
    const float* normals         = (const float*)d_in[3];
    const float* light_location  = (const float*)d_in[4];
    const float* light_ambient   = (const float*)d_in[5];
    const float* light_diffuse   = (const float*)d_in[6];
    const float* light_specular  = (const float*)d_in[7];
    const float* mat_ambient     = (const float*)d_in[8];
    const float* mat_diffuse     = (const float*)d_in[9];
    const float* mat_specular    = (const float*)d_in[10];
    const float* camera_position = (const float*)d_in[11];
    const int*   shininess       = (const int*)d_in[12];
    float*       out             = (float*)d_out;

    const int n_pix = in_sizes[0] / K;   // N*H*W = 524288
    const int block = 256;
    const int grid  = (n_pix + block - 1) / block;

    shading_compositor_kernel<<<grid, block, 0, stream>>>(
        idx, dists, points, normals, light_location, light_ambient,
        light_diffuse, light_specular, mat_ambient, mat_diffuse,
        mat_specular, camera_position, shininess, out, n_pix);
}

// Round 2
// 124.417 us; speedup vs baseline: 1.0883x; 1.0883x over previous
//
#include <hip/hip_runtime.h>

#define K 8

// ---------- prepack: points+normals -> 32B interleaved records in ws ----------
// rec[2i]   = {px, py, pz, 0}
// rec[2i+1] = {nx, ny, nz, 0}
__global__ __launch_bounds__(256) void pack_pn_kernel(
    const float* __restrict__ points,
    const float* __restrict__ normals,
    float4*      __restrict__ rec,
    int P)
{
    const int i = blockIdx.x * blockDim.x + threadIdx.x;
    if (i >= P) return;
    const size_t b = (size_t)i * 3;
    rec[2 * i]     = make_float4(points[b],  points[b + 1],  points[b + 2],  0.0f);
    rec[2 * i + 1] = make_float4(normals[b], normals[b + 1], normals[b + 2], 0.0f);
}

// ---------- shared shading math ----------
struct ShadeConsts {
    float Lx, Ly, Lz, Cx, Cy, Cz;
    float amb0, amb1, amb2, dif0, dif1, dif2, spc0, spc1, spc2;
    int shin;
};

template <bool PACKED>
__global__ __launch_bounds__(256) void shading_compositor_kernel(
    const int*    __restrict__ idx,
    const float*  __restrict__ dists,
    const float*  __restrict__ points,
    const float*  __restrict__ normals,
    const float4* __restrict__ rec,       // packed table (PACKED path)
    const float*  __restrict__ light_location,
    const float*  __restrict__ light_ambient,
    const float*  __restrict__ light_diffuse,
    const float*  __restrict__ light_specular,
    const float*  __restrict__ mat_ambient,
    const float*  __restrict__ mat_diffuse,
    const float*  __restrict__ mat_specular,
    const float*  __restrict__ camera_position,
    const int*    __restrict__ shininess_p,
    float*        __restrict__ out,
    int n_pix)
{
    const int p = blockIdx.x * blockDim.x + threadIdx.x;
    if (p >= n_pix) return;

    const float Lx = light_location[0], Ly = light_location[1], Lz = light_location[2];
    const float Cx = camera_position[0], Cy = camera_position[1], Cz = camera_position[2];
    const float amb0 = light_ambient[0] * mat_ambient[0];
    const float amb1 = light_ambient[1] * mat_ambient[1];
    const float amb2 = light_ambient[2] * mat_ambient[2];
    const float dif0 = light_diffuse[0] * mat_diffuse[0];
    const float dif1 = light_diffuse[1] * mat_diffuse[1];
    const float dif2 = light_diffuse[2] * mat_diffuse[2];
    const float spc0 = light_specular[0] * mat_specular[0];
    const float spc1 = light_specular[1] * mat_specular[1];
    const float spc2 = light_specular[2] * mat_specular[2];
    const int   shin = shininess_p[0];

    const int4*   idxv = reinterpret_cast<const int4*>(idx   + (size_t)p * K);
    const float4* dstv = reinterpret_cast<const float4*>(dists + (size_t)p * K);
    int4   i0 = idxv[0], i1 = idxv[1];
    float4 d0 = dstv[0], d1 = dstv[1];

    int   ik[K] = {i0.x, i0.y, i0.z, i0.w, i1.x, i1.y, i1.z, i1.w};
    float dk[K] = {d0.x, d0.y, d0.z, d0.w, d1.x, d1.y, d1.z, d1.w};

    float w[K];
    float wsum = 0.f;
#pragma unroll
    for (int k = 0; k < K; ++k) {
        float d = dk[k];
        float m = (d != -1.0f) ? d : 0.0f;
        w[k] = m;
        wsum += fabsf(m);
    }
    const float winv = 1.0f / fmaxf(wsum, 1e-12f);

    // accumulate with raw w[k]; scale by winv once at the end
    float acc0 = 0.f, acc1 = 0.f, acc2 = 0.f;

#pragma unroll
    for (int k = 0; k < K; ++k) {
        const int ii = (ik[k] < 0) ? 0 : ik[k];
        float px, py, pz, nx, ny, nz;
        if (PACKED) {
            const float4 pr = rec[2 * (size_t)ii];
            const float4 nr = rec[2 * (size_t)ii + 1];
            px = pr.x; py = pr.y; pz = pr.z;
            nx = nr.x; ny = nr.y; nz = nr.z;
        } else {
            const size_t base = (size_t)ii * 3;
            px = points[base];  py = points[base + 1];  pz = points[base + 2];
            nx = normals[base]; ny = normals[base + 1]; nz = normals[base + 2];
        }

        float lx = Lx - px, ly = Ly - py, lz = Lz - pz;
        float ll = lx * lx + ly * ly + lz * lz;
        float li = (ll > 1e-12f) ? rsqrtf(ll) : 1e6f;
        lx *= li; ly *= li; lz *= li;

        const float cosv = nx * lx + ny * ly + nz * lz;

        float vx = Cx - px, vy = Cy - py, vz = Cz - pz;
        float vv = vx * vx + vy * vy + vz * vz;
        float vi = (vv > 1e-12f) ? rsqrtf(vv) : 1e6f;
        vx *= vi; vy *= vi; vz *= vi;

        const float c2 = 2.0f * cosv;
        const float rx = c2 * nx - lx;
        const float ry = c2 * ny - ly;
        const float rz = c2 * nz - lz;

        float alpha = fmaxf(vx * rx + vy * ry + vz * rz, 0.0f);
        if (!(cosv > 0.0f)) alpha = 0.0f;

        float sp = 1.0f, b = alpha;
        int e = shin;
        while (e > 0) {
            if (e & 1) sp *= b;
            b *= b;
            e >>= 1;
        }

        const float rc = fmaxf(cosv, 0.0f);
        const float wk = w[k];
        acc0 += wk * (amb0 + dif0 * rc + spc0 * sp);
        acc1 += wk * (amb1 + dif1 * rc + spc1 * sp);
        acc2 += wk * (amb2 + dif2 * rc + spc2 * sp);
    }

    float* o = out + (size_t)p * 3;
    o[0] = acc0 * winv;
    o[1] = acc1 * winv;
    o[2] = acc2 * winv;
}

extern "C" void kernel_launch(void* const* d_in, const int* in_sizes, int n_in,
                              void* d_out, int out_size, void* d_ws, size_t ws_size,
                              hipStream_t stream) {
    const int*   idx             = (const int*)d_in[0];
    const float* dists           = (const float*)d_in[1];
    const float* points          = (const float*)d_in[2];
    const float* normals         = (const float*)d_in[3];
    const float* light_location  = (const float*)d_in[4];
    const float* light_ambient   = (const float*)d_in[5];
    const float* light_diffuse   = (const float*)d_in[6];
    const float* light_specular  = (const float*)d_in[7];
    const float* mat_ambient     = (const float*)d_in[8];
    const float* mat_diffuse     = (const float*)d_in[9];
    const float* mat_specular    = (const float*)d_in[10];
    const float* camera_position = (const float*)d_in[11];
    const int*   shininess       = (const int*)d_in[12];
    float*       out             = (float*)d_out;

    const int n_pix = in_sizes[0] / K;       // N*H*W
    const int P     = in_sizes[2] / 3;       // number of points

    const int block = 256;
    const int grid  = (n_pix + block - 1) / block;

    const size_t need = (size_t)P * 2 * sizeof(float4);
    if (ws_size >= need) {
        float4* rec = (float4*)d_ws;
        pack_pn_kernel<<<(P + block - 1) / block, block, 0, stream>>>(points, normals, rec, P);
        shading_compositor_kernel<true><<<grid, block, 0, stream>>>(
            idx, dists, points, normals, rec, light_location, light_ambient,
            light_diffuse, light_specular, mat_ambient, mat_diffuse,
            mat_specular, camera_position, shininess, out, n_pix);
    } else {
        shading_compositor_kernel<false><<<grid, block, 0, stream>>>(
            idx, dists, points, normals, nullptr, light_location, light_ambient,
            light_diffuse, light_specular, mat_ambient, mat_diffuse,
            mat_specular, camera_position, shininess, out, n_pix);
    }
}